// Round 1
// baseline (639.780 us; speedup 1.0000x reference)
//
#include <hip/hip_runtime.h>
#include <stdint.h>

#define NB 8
#define LL 2048
#define SS 2048
#define DD 1024

typedef __attribute__((ext_vector_type(4))) float f32x4;
typedef __attribute__((ext_vector_type(8))) short bf16x8;
typedef __attribute__((ext_vector_type(4))) unsigned short u16x4;
typedef __attribute__((ext_vector_type(8))) unsigned short u16x8;

__device__ __forceinline__ unsigned short f2bf(float x) {
    unsigned int u = __builtin_bit_cast(unsigned int, x);
    u += 0x7FFFu + ((u >> 16) & 1u);   // round-to-nearest-even
    return (unsigned short)(u >> 16);
}
__device__ __forceinline__ float bf2f(unsigned short h) {
    unsigned int u = ((unsigned int)h) << 16;
    return __builtin_bit_cast(float, u);
}

__device__ __forceinline__ void gload16(const void* g, void* l) {
    __builtin_amdgcn_global_load_lds(
        (const __attribute__((address_space(1))) unsigned int*)g,
        (__attribute__((address_space(3))) unsigned int*)l, 16, 0, 0);
}

// Stage a [128][32] bf16 tile (linear LDS) from row-major [*, ldk] bf16 source.
// g must already point at (row0, k0). 512 x 16B segments, 2 per thread.
__device__ __forceinline__ void stage_bf16(unsigned short* lds, const unsigned short* g,
                                           int ldk, int tid) {
#pragma unroll
    for (int i = 0; i < 2; i++) {
        int seg = i * 256 + tid;
        int r = seg >> 2, s8 = (seg & 3) * 8;
        gload16(g + (size_t)r * ldk + s8, lds + seg * 8);
    }
}

// Stage a [128][32] tile from fp32 source, splitting to hi/lo bf16 in registers.
__device__ __forceinline__ void stage_cvt(unsigned short* ldsH, unsigned short* ldsL,
                                          const float* g, int ldk, int tid) {
#pragma unroll
    for (int i = 0; i < 4; i++) {
        int seg = i * 256 + tid;
        int r = seg >> 3, c4 = (seg & 7) * 4;
        f32x4 x = *(const f32x4*)(g + (size_t)r * ldk + c4);
        u16x4 hv, lv;
#pragma unroll
        for (int j = 0; j < 4; j++) {
            unsigned short h = f2bf(x[j]);
            hv[j] = h;
            lv[j] = f2bf(x[j] - bf2f(h));
        }
        *(u16x4*)&ldsH[r * 32 + c4] = hv;
        *(u16x4*)&ldsL[r * 32 + c4] = lv;
    }
}

__device__ __forceinline__ bf16x8 ldfrag(const unsigned short* lds, int row, int l4) {
    return *(const bf16x8*)&lds[row * 32 + l4 * 8];
}

// ---------------- W split ----------------
__global__ __launch_bounds__(256) void k_splitw(const float* __restrict__ W,
                                                unsigned short* __restrict__ Whi,
                                                unsigned short* __restrict__ Wlo) {
    int idx = blockIdx.x * 256 + threadIdx.x;  // over 262144 float4
    f32x4 x = *(const f32x4*)(W + (size_t)idx * 4);
    u16x4 h, l;
#pragma unroll
    for (int j = 0; j < 4; j++) {
        unsigned short hh = f2bf(x[j]);
        h[j] = hh;
        l[j] = f2bf(x[j] - bf2f(hh));
    }
    *(u16x4*)(Whi + (size_t)idx * 4) = h;
    *(u16x4*)(Wlo + (size_t)idx * 4) = l;
}

// ---------------- V transpose: [n,s,d] f32 -> [n,d,s] bf16 ----------------
__global__ __launch_bounds__(256) void k_transv(const float* __restrict__ V,
                                                unsigned short* __restrict__ Vt) {
    __shared__ float t[64][65];
    const int n = blockIdx.z;
    const int s0 = blockIdx.x * 64, d0 = blockIdx.y * 64;
    const int tid = threadIdx.x;
    const float* src = V + ((size_t)n * SS + s0) * DD + d0;
#pragma unroll
    for (int i = 0; i < 4; i++) {
        int seg = i * 256 + tid;
        int r = seg >> 4, c4 = (seg & 15) * 4;
        f32x4 x = *(const f32x4*)(src + (size_t)r * DD + c4);
        t[r][c4 + 0] = x[0]; t[r][c4 + 1] = x[1];
        t[r][c4 + 2] = x[2]; t[r][c4 + 3] = x[3];
    }
    __syncthreads();
    const int dl = tid >> 2, sc = (tid & 3) * 16;
    u16x8 o0, o1;
#pragma unroll
    for (int j = 0; j < 8; j++) o0[j] = f2bf(t[sc + j][dl]);
#pragma unroll
    for (int j = 0; j < 8; j++) o1[j] = f2bf(t[sc + 8 + j][dl]);
    unsigned short* dst = Vt + ((size_t)n * DD + d0 + dl) * SS + s0 + sc;
    *(u16x8*)dst = o0;
    *(u16x8*)(dst + 8) = o1;
}

// ---------------- q_proj GEMM: [16384,1024] = query x W^T + b, split output ----------------
__global__ __launch_bounds__(256, 2) void k_qproj(const float* __restrict__ Q,
                                                  const unsigned short* __restrict__ Whi,
                                                  const unsigned short* __restrict__ Wlo,
                                                  const float* __restrict__ bias,
                                                  unsigned short* __restrict__ QPhi,
                                                  unsigned short* __restrict__ QPlo) {
    __shared__ __align__(16) unsigned short Ah[128 * 32], Al[128 * 32];
    __shared__ __align__(16) unsigned short Bh[128 * 32], Bl[128 * 32];
    const int tid = threadIdx.x;
    const int lane = tid & 63, wv = tid >> 6;
    const int wr = wv >> 1, wc = wv & 1;
    const int l16 = lane & 15, l4 = lane >> 4;
    const size_t row0 = (size_t)blockIdx.x * 128;
    const int col0 = blockIdx.y * 128;

    f32x4 acc[4][4];
#pragma unroll
    for (int mi = 0; mi < 4; mi++)
#pragma unroll
        for (int ni = 0; ni < 4; ni++) acc[mi][ni] = (f32x4){0.f, 0.f, 0.f, 0.f};

    for (int kt = 0; kt < DD / 32; ++kt) {
        int k0 = kt * 32;
        stage_cvt(Ah, Al, Q + row0 * DD + k0, DD, tid);
        stage_bf16(Bh, Whi + (size_t)col0 * DD + k0, DD, tid);
        stage_bf16(Bl, Wlo + (size_t)col0 * DD + k0, DD, tid);
        __syncthreads();
        bf16x8 ah[4], al[4], bh[4], bl[4];
#pragma unroll
        for (int mi = 0; mi < 4; mi++) {
            int r = wr * 64 + mi * 16 + l16;
            ah[mi] = ldfrag(Ah, r, l4);
            al[mi] = ldfrag(Al, r, l4);
        }
#pragma unroll
        for (int ni = 0; ni < 4; ni++) {
            int r = wc * 64 + ni * 16 + l16;
            bh[ni] = ldfrag(Bh, r, l4);
            bl[ni] = ldfrag(Bl, r, l4);
        }
#pragma unroll
        for (int mi = 0; mi < 4; mi++)
#pragma unroll
            for (int ni = 0; ni < 4; ni++) {
                acc[mi][ni] = __builtin_amdgcn_mfma_f32_16x16x32_bf16(ah[mi], bh[ni], acc[mi][ni], 0, 0, 0);
                acc[mi][ni] = __builtin_amdgcn_mfma_f32_16x16x32_bf16(ah[mi], bl[ni], acc[mi][ni], 0, 0, 0);
                acc[mi][ni] = __builtin_amdgcn_mfma_f32_16x16x32_bf16(al[mi], bh[ni], acc[mi][ni], 0, 0, 0);
            }
        __syncthreads();
    }
#pragma unroll
    for (int mi = 0; mi < 4; mi++)
#pragma unroll
        for (int ni = 0; ni < 4; ni++) {
            int col = col0 + wc * 64 + ni * 16 + l16;
            float bv = bias[col];
#pragma unroll
            for (int r = 0; r < 4; r++) {
                size_t row = row0 + wr * 64 + mi * 16 + l4 * 4 + r;
                float v = acc[mi][ni][r] + bv;
                unsigned short h = f2bf(v);
                QPhi[row * DD + col] = h;
                QPlo[row * DD + col] = f2bf(v - bf2f(h));
            }
        }
}

// ---------------- score GEMM: scores[n, lb, 2048] = qp x key^T (3-pass split) ----------------
__global__ __launch_bounds__(256, 2) void k_score(const unsigned short* __restrict__ QPhi,
                                                  const unsigned short* __restrict__ QPlo,
                                                  const float* __restrict__ Key,
                                                  float* __restrict__ Sc,
                                                  int band0, int lb) {
    __shared__ __align__(16) unsigned short Ah[128 * 32], Al[128 * 32];
    __shared__ __align__(16) unsigned short Bh[128 * 32], Bl[128 * 32];
    const int tid = threadIdx.x;
    const int lane = tid & 63, wv = tid >> 6;
    const int wr = wv >> 1, wc = wv & 1;
    const int l16 = lane & 15, l4 = lane >> 4;
    const int n = blockIdx.z;
    const size_t arow0 = (size_t)n * LL + band0 + blockIdx.x * 128;  // rows in QP
    const size_t krow0 = (size_t)n * SS + blockIdx.y * 128;          // rows in Key
    const int col0 = blockIdx.y * 128;

    f32x4 acc[4][4];
#pragma unroll
    for (int mi = 0; mi < 4; mi++)
#pragma unroll
        for (int ni = 0; ni < 4; ni++) acc[mi][ni] = (f32x4){0.f, 0.f, 0.f, 0.f};

    for (int kt = 0; kt < DD / 32; ++kt) {
        int k0 = kt * 32;
        stage_bf16(Ah, QPhi + arow0 * DD + k0, DD, tid);
        stage_bf16(Al, QPlo + arow0 * DD + k0, DD, tid);
        stage_cvt(Bh, Bl, Key + krow0 * DD + k0, DD, tid);
        __syncthreads();
        bf16x8 ah[4], al[4], bh[4], bl[4];
#pragma unroll
        for (int mi = 0; mi < 4; mi++) {
            int r = wr * 64 + mi * 16 + l16;
            ah[mi] = ldfrag(Ah, r, l4);
            al[mi] = ldfrag(Al, r, l4);
        }
#pragma unroll
        for (int ni = 0; ni < 4; ni++) {
            int r = wc * 64 + ni * 16 + l16;
            bh[ni] = ldfrag(Bh, r, l4);
            bl[ni] = ldfrag(Bl, r, l4);
        }
#pragma unroll
        for (int mi = 0; mi < 4; mi++)
#pragma unroll
            for (int ni = 0; ni < 4; ni++) {
                acc[mi][ni] = __builtin_amdgcn_mfma_f32_16x16x32_bf16(ah[mi], bh[ni], acc[mi][ni], 0, 0, 0);
                acc[mi][ni] = __builtin_amdgcn_mfma_f32_16x16x32_bf16(ah[mi], bl[ni], acc[mi][ni], 0, 0, 0);
                acc[mi][ni] = __builtin_amdgcn_mfma_f32_16x16x32_bf16(al[mi], bh[ni], acc[mi][ni], 0, 0, 0);
            }
        __syncthreads();
    }
#pragma unroll
    for (int mi = 0; mi < 4; mi++)
#pragma unroll
        for (int ni = 0; ni < 4; ni++) {
            int col = col0 + wc * 64 + ni * 16 + l16;
#pragma unroll
            for (int r = 0; r < 4; r++) {
                int rl = blockIdx.x * 128 + wr * 64 + mi * 16 + l4 * 4 + r;
                Sc[((size_t)n * lb + rl) * SS + col] = acc[mi][ni][r];
            }
        }
}

// ---------------- row softmax: scores f32 -> P bf16 ----------------
__global__ __launch_bounds__(256) void k_softmax(const float* __restrict__ Sc,
                                                 unsigned short* __restrict__ P) {
    const size_t row = blockIdx.x;
    const float* src = Sc + row * SS;
    const int tid = threadIdx.x;
    const int lane = tid & 63, wv = tid >> 6;
    f32x4 v[2];
    float m = -3.4e38f;
#pragma unroll
    for (int i = 0; i < 2; i++) {
        v[i] = *(const f32x4*)(src + (size_t)(tid + i * 256) * 4);
#pragma unroll
        for (int j = 0; j < 4; j++) m = fmaxf(m, v[i][j]);
    }
#pragma unroll
    for (int o = 32; o > 0; o >>= 1) m = fmaxf(m, __shfl_xor(m, o, 64));
    __shared__ float redm[4];
    __shared__ float reds[4];
    if (lane == 0) redm[wv] = m;
    __syncthreads();
    m = fmaxf(fmaxf(redm[0], redm[1]), fmaxf(redm[2], redm[3]));
    float s = 0.f;
#pragma unroll
    for (int i = 0; i < 2; i++)
#pragma unroll
        for (int j = 0; j < 4; j++) {
            v[i][j] = __expf(v[i][j] - m);
            s += v[i][j];
        }
#pragma unroll
    for (int o = 32; o > 0; o >>= 1) s += __shfl_xor(s, o, 64);
    if (lane == 0) reds[wv] = s;
    __syncthreads();
    s = reds[0] + reds[1] + reds[2] + reds[3];
    float inv = 1.0f / s;
#pragma unroll
    for (int i = 0; i < 2; i++) {
        u16x4 h;
#pragma unroll
        for (int j = 0; j < 4; j++) h[j] = f2bf(v[i][j] * inv);
        *(u16x4*)(P + row * SS + (size_t)(tid + i * 256) * 4) = h;
    }
}

// ---------------- PV GEMM: out[n, lb, 1024] = P x Vt^T (bf16) ----------------
__global__ __launch_bounds__(256, 2) void k_pv(const unsigned short* __restrict__ P,
                                               const unsigned short* __restrict__ Vt,
                                               float* __restrict__ Out,
                                               int band0, int lb) {
    __shared__ __align__(16) unsigned short Ab[128 * 32], Bb[128 * 32];
    const int tid = threadIdx.x;
    const int lane = tid & 63, wv = tid >> 6;
    const int wr = wv >> 1, wc = wv & 1;
    const int l16 = lane & 15, l4 = lane >> 4;
    const int n = blockIdx.z;
    const size_t arow0 = (size_t)n * lb + blockIdx.x * 128;  // P rows (band local)
    const size_t brow0 = (size_t)n * DD + blockIdx.y * 128;  // Vt rows
    const int col0 = blockIdx.y * 128;

    f32x4 acc[4][4];
#pragma unroll
    for (int mi = 0; mi < 4; mi++)
#pragma unroll
        for (int ni = 0; ni < 4; ni++) acc[mi][ni] = (f32x4){0.f, 0.f, 0.f, 0.f};

    for (int kt = 0; kt < SS / 32; ++kt) {
        int k0 = kt * 32;
        stage_bf16(Ab, P + arow0 * SS + k0, SS, tid);
        stage_bf16(Bb, Vt + brow0 * SS + k0, SS, tid);
        __syncthreads();
        bf16x8 a[4], b[4];
#pragma unroll
        for (int mi = 0; mi < 4; mi++) a[mi] = ldfrag(Ab, wr * 64 + mi * 16 + l16, l4);
#pragma unroll
        for (int ni = 0; ni < 4; ni++) b[ni] = ldfrag(Bb, wc * 64 + ni * 16 + l16, l4);
#pragma unroll
        for (int mi = 0; mi < 4; mi++)
#pragma unroll
            for (int ni = 0; ni < 4; ni++)
                acc[mi][ni] = __builtin_amdgcn_mfma_f32_16x16x32_bf16(a[mi], b[ni], acc[mi][ni], 0, 0, 0);
        __syncthreads();
    }
#pragma unroll
    for (int mi = 0; mi < 4; mi++)
#pragma unroll
        for (int ni = 0; ni < 4; ni++) {
            int col = col0 + wc * 64 + ni * 16 + l16;
#pragma unroll
            for (int r = 0; r < 4; r++) {
                size_t row = (size_t)n * LL + band0 + blockIdx.x * 128 + wr * 64 + mi * 16 + l4 * 4 + r;
                Out[row * DD + col] = acc[mi][ni][r];
            }
        }
}

extern "C" void kernel_launch(void* const* d_in, const int* in_sizes, int n_in,
                              void* d_out, int out_size, void* d_ws, size_t ws_size,
                              hipStream_t stream) {
    const float* key   = (const float*)d_in[0];
    const float* query = (const float*)d_in[1];
    const float* value = (const float*)d_in[2];
    const float* W     = (const float*)d_in[3];
    const float* bias  = (const float*)d_in[4];
    float* out = (float*)d_out;
    char* ws = (char*)d_ws;

    const size_t szW  = (size_t)DD * DD * 2;        // 2 MiB
    const size_t szQP = (size_t)NB * LL * DD * 2;   // 32 MiB
    const size_t szVt = (size_t)NB * DD * SS * 2;   // 32 MiB
    size_t off = 0;
    unsigned short* Whi = (unsigned short*)(ws + off); off += szW;
    unsigned short* Wlo = (unsigned short*)(ws + off); off += szW;
    unsigned short* QPhi = (unsigned short*)(ws + off); off += szQP;
    unsigned short* QPlo = (unsigned short*)(ws + off); off += szQP;
    unsigned short* Vt  = (unsigned short*)(ws + off); off += szVt;
    // band buffers: pick largest band size that fits the remaining workspace
    int lb = 512;
    while (lb > 128 && off + (size_t)NB * lb * SS * 6 > ws_size) lb >>= 1;
    float* Sc = (float*)(ws + off); off += (size_t)NB * lb * SS * 4;
    unsigned short* P = (unsigned short*)(ws + off);

    k_splitw<<<dim3((DD * DD) / (4 * 256)), 256, 0, stream>>>(W, Whi, Wlo);
    k_transv<<<dim3(SS / 64, DD / 64, NB), 256, 0, stream>>>(value, Vt);
    k_qproj<<<dim3((NB * LL) / 128, DD / 128), 256, 0, stream>>>(query, Whi, Wlo, bias, QPhi, QPlo);

    const int nbands = LL / lb;
    for (int b = 0; b < nbands; b++) {
        int band0 = b * lb;
        k_score<<<dim3(lb / 128, SS / 128, NB), 256, 0, stream>>>(QPhi, QPlo, key, Sc, band0, lb);
        k_softmax<<<dim3(NB * lb), 256, 0, stream>>>(Sc, P);
        k_pv<<<dim3(lb / 128, DD / 128, NB), 256, 0, stream>>>(P, Vt, out, band0, lb);
    }
    (void)in_sizes; (void)n_in; (void)out_size; (void)ws_size;
}

// Round 2
// 557.736 us; speedup vs baseline: 1.1471x; 1.1471x over previous
//
#include <hip/hip_runtime.h>
#include <stdint.h>

#define NB 8
#define LL 2048
#define SS 2048
#define DD 1024

typedef __attribute__((ext_vector_type(4))) float f32x4;
typedef __attribute__((ext_vector_type(8))) short bf16x8;
typedef __attribute__((ext_vector_type(8))) _Float16 f16x8;
typedef __attribute__((ext_vector_type(4))) unsigned short u16x4;
typedef __attribute__((ext_vector_type(8))) unsigned short u16x8;

__device__ __forceinline__ unsigned short f2bf(float x) {
    unsigned int u = __builtin_bit_cast(unsigned int, x);
    u += 0x7FFFu + ((u >> 16) & 1u);   // round-to-nearest-even
    return (unsigned short)(u >> 16);
}
__device__ __forceinline__ float bf2f(unsigned short h) {
    unsigned int u = ((unsigned int)h) << 16;
    return __builtin_bit_cast(float, u);
}
__device__ __forceinline__ unsigned short f2h(float x) {
    return __builtin_bit_cast(unsigned short, (_Float16)x);
}

__device__ __forceinline__ void gload16(const void* g, void* l) {
    __builtin_amdgcn_global_load_lds(
        (const __attribute__((address_space(1))) unsigned int*)g,
        (__attribute__((address_space(3))) unsigned int*)l, 16, 0, 0);
}

// Stage a [128][32] 16-bit tile (linear LDS) from row-major [*, ldk] source via global_load_lds.
__device__ __forceinline__ void stage_16b(unsigned short* lds, const unsigned short* g,
                                          int ldk, int tid) {
#pragma unroll
    for (int i = 0; i < 2; i++) {
        int seg = i * 256 + tid;
        int r = seg >> 2, s8 = (seg & 3) * 8;
        gload16(g + (size_t)r * ldk + s8, lds + seg * 8);
    }
}

// Stage a [128][32] tile from fp32 source, splitting to hi/lo bf16 in registers.
__device__ __forceinline__ void stage_cvt(unsigned short* ldsH, unsigned short* ldsL,
                                          const float* g, int ldk, int tid) {
#pragma unroll
    for (int i = 0; i < 4; i++) {
        int seg = i * 256 + tid;
        int r = seg >> 3, c4 = (seg & 7) * 4;
        f32x4 x = *(const f32x4*)(g + (size_t)r * ldk + c4);
        u16x4 hv, lv;
#pragma unroll
        for (int j = 0; j < 4; j++) {
            unsigned short h = f2bf(x[j]);
            hv[j] = h;
            lv[j] = f2bf(x[j] - bf2f(h));
        }
        *(u16x4*)&ldsH[r * 32 + c4] = hv;
        *(u16x4*)&ldsL[r * 32 + c4] = lv;
    }
}

// Stage a [128][32] tile from fp32 source converted to fp16 (bits in ushort LDS).
__device__ __forceinline__ void stage_cvt16(unsigned short* lds, const float* g,
                                            int ldk, int tid) {
#pragma unroll
    for (int i = 0; i < 4; i++) {
        int seg = i * 256 + tid;
        int r = seg >> 3, c4 = (seg & 7) * 4;
        f32x4 x = *(const f32x4*)(g + (size_t)r * ldk + c4);
        u16x4 hv;
#pragma unroll
        for (int j = 0; j < 4; j++) hv[j] = f2h(x[j]);
        *(u16x4*)&lds[r * 32 + c4] = hv;
    }
}

__device__ __forceinline__ bf16x8 ldfrag(const unsigned short* lds, int row, int l4) {
    return *(const bf16x8*)&lds[row * 32 + l4 * 8];
}
__device__ __forceinline__ f16x8 ldfrag16(const unsigned short* lds, int row, int l4) {
    return *(const f16x8*)&lds[row * 32 + l4 * 8];
}

// ---------------- W -> fp16 ----------------
__global__ __launch_bounds__(256) void k_wf16(const float* __restrict__ W,
                                              unsigned short* __restrict__ Wf) {
    int idx = blockIdx.x * 256 + threadIdx.x;  // over DD*DD/4 float4
    f32x4 x = *(const f32x4*)(W + (size_t)idx * 4);
    u16x4 h;
#pragma unroll
    for (int j = 0; j < 4; j++) h[j] = f2h(x[j]);
    *(u16x4*)(Wf + (size_t)idx * 4) = h;
}

// ---------------- Key -> hi/lo bf16 split ----------------
__global__ __launch_bounds__(256) void k_splitk(const float* __restrict__ K,
                                                unsigned short* __restrict__ Khi,
                                                unsigned short* __restrict__ Klo) {
    size_t idx = (size_t)blockIdx.x * 256 + threadIdx.x;  // over NB*SS*DD/4 float4
    f32x4 x = *(const f32x4*)(K + idx * 4);
    u16x4 h, l;
#pragma unroll
    for (int j = 0; j < 4; j++) {
        unsigned short hh = f2bf(x[j]);
        h[j] = hh;
        l[j] = f2bf(x[j] - bf2f(hh));
    }
    *(u16x4*)(Khi + idx * 4) = h;
    *(u16x4*)(Klo + idx * 4) = l;
}

// ---------------- V transpose: [n,s,d] f32 -> [n,d,s] bf16 ----------------
__global__ __launch_bounds__(256) void k_transv(const float* __restrict__ V,
                                                unsigned short* __restrict__ Vt) {
    __shared__ float t[64][65];
    const int n = blockIdx.z;
    const int s0 = blockIdx.x * 64, d0 = blockIdx.y * 64;
    const int tid = threadIdx.x;
    const float* src = V + ((size_t)n * SS + s0) * DD + d0;
#pragma unroll
    for (int i = 0; i < 4; i++) {
        int seg = i * 256 + tid;
        int r = seg >> 4, c4 = (seg & 15) * 4;
        f32x4 x = *(const f32x4*)(src + (size_t)r * DD + c4);
        t[r][c4 + 0] = x[0]; t[r][c4 + 1] = x[1];
        t[r][c4 + 2] = x[2]; t[r][c4 + 3] = x[3];
    }
    __syncthreads();
    const int dl = tid >> 2, sc = (tid & 3) * 16;
    u16x8 o0, o1;
#pragma unroll
    for (int j = 0; j < 8; j++) o0[j] = f2bf(t[sc + j][dl]);
#pragma unroll
    for (int j = 0; j < 8; j++) o1[j] = f2bf(t[sc + 8 + j][dl]);
    unsigned short* dst = Vt + ((size_t)n * DD + d0 + dl) * SS + s0 + sc;
    *(u16x8*)dst = o0;
    *(u16x8*)(dst + 8) = o1;
}

// ---------------- q_proj GEMM: fp16 single-pass, split bf16 output ----------------
__global__ __launch_bounds__(256, 2) void k_qproj(const float* __restrict__ Q,
                                                  const unsigned short* __restrict__ Wf,
                                                  const float* __restrict__ bias,
                                                  unsigned short* __restrict__ QPhi,
                                                  unsigned short* __restrict__ QPlo) {
    __shared__ __align__(16) unsigned short Aq[128 * 32], Bw[128 * 32];
    const int tid = threadIdx.x;
    const int lane = tid & 63, wv = tid >> 6;
    const int wr = wv >> 1, wc = wv & 1;
    const int l16 = lane & 15, l4 = lane >> 4;
    const size_t row0 = (size_t)blockIdx.x * 128;
    const int col0 = blockIdx.y * 128;

    f32x4 acc[4][4];
#pragma unroll
    for (int mi = 0; mi < 4; mi++)
#pragma unroll
        for (int ni = 0; ni < 4; ni++) acc[mi][ni] = (f32x4){0.f, 0.f, 0.f, 0.f};

    for (int kt = 0; kt < DD / 32; ++kt) {
        int k0 = kt * 32;
        stage_cvt16(Aq, Q + row0 * DD + k0, DD, tid);
        stage_16b(Bw, Wf + (size_t)col0 * DD + k0, DD, tid);
        __syncthreads();
        f16x8 a[4], b[4];
#pragma unroll
        for (int mi = 0; mi < 4; mi++) a[mi] = ldfrag16(Aq, wr * 64 + mi * 16 + l16, l4);
#pragma unroll
        for (int ni = 0; ni < 4; ni++) b[ni] = ldfrag16(Bw, wc * 64 + ni * 16 + l16, l4);
#pragma unroll
        for (int mi = 0; mi < 4; mi++)
#pragma unroll
            for (int ni = 0; ni < 4; ni++)
                acc[mi][ni] = __builtin_amdgcn_mfma_f32_16x16x32_f16(a[mi], b[ni], acc[mi][ni], 0, 0, 0);
        __syncthreads();
    }
#pragma unroll
    for (int mi = 0; mi < 4; mi++)
#pragma unroll
        for (int ni = 0; ni < 4; ni++) {
            int col = col0 + wc * 64 + ni * 16 + l16;
            float bv = bias[col];
#pragma unroll
            for (int r = 0; r < 4; r++) {
                size_t row = row0 + wr * 64 + mi * 16 + l4 * 4 + r;
                float v = acc[mi][ni][r] + bv;
                unsigned short h = f2bf(v);
                QPhi[row * DD + col] = h;
                QPlo[row * DD + col] = f2bf(v - bf2f(h));
            }
        }
}

// ---------------- score GEMM: scores[n, lb, 2048] = qp x key^T (3-pass split) ----------------
template <bool PRESPLIT>
__global__ __launch_bounds__(256, 2) void k_score(const unsigned short* __restrict__ QPhi,
                                                  const unsigned short* __restrict__ QPlo,
                                                  const unsigned short* __restrict__ Khi,
                                                  const unsigned short* __restrict__ Klo,
                                                  const float* __restrict__ Key,
                                                  float* __restrict__ Sc,
                                                  int band0, int lb) {
    __shared__ __align__(16) unsigned short Ah[128 * 32], Al[128 * 32];
    __shared__ __align__(16) unsigned short Bh[128 * 32], Bl[128 * 32];
    const int tid = threadIdx.x;
    const int lane = tid & 63, wv = tid >> 6;
    const int wr = wv >> 1, wc = wv & 1;
    const int l16 = lane & 15, l4 = lane >> 4;
    const int n = blockIdx.z;
    const size_t arow0 = (size_t)n * LL + band0 + blockIdx.x * 128;  // rows in QP
    const size_t krow0 = (size_t)n * SS + blockIdx.y * 128;          // rows in Key
    const int col0 = blockIdx.y * 128;

    f32x4 acc[4][4];
#pragma unroll
    for (int mi = 0; mi < 4; mi++)
#pragma unroll
        for (int ni = 0; ni < 4; ni++) acc[mi][ni] = (f32x4){0.f, 0.f, 0.f, 0.f};

    for (int kt = 0; kt < DD / 32; ++kt) {
        int k0 = kt * 32;
        stage_16b(Ah, QPhi + arow0 * DD + k0, DD, tid);
        stage_16b(Al, QPlo + arow0 * DD + k0, DD, tid);
        if constexpr (PRESPLIT) {
            stage_16b(Bh, Khi + krow0 * DD + k0, DD, tid);
            stage_16b(Bl, Klo + krow0 * DD + k0, DD, tid);
        } else {
            stage_cvt(Bh, Bl, Key + krow0 * DD + k0, DD, tid);
        }
        __syncthreads();
        bf16x8 ah[4], al[4], bh[4], bl[4];
#pragma unroll
        for (int mi = 0; mi < 4; mi++) {
            int r = wr * 64 + mi * 16 + l16;
            ah[mi] = ldfrag(Ah, r, l4);
            al[mi] = ldfrag(Al, r, l4);
        }
#pragma unroll
        for (int ni = 0; ni < 4; ni++) {
            int r = wc * 64 + ni * 16 + l16;
            bh[ni] = ldfrag(Bh, r, l4);
            bl[ni] = ldfrag(Bl, r, l4);
        }
#pragma unroll
        for (int mi = 0; mi < 4; mi++)
#pragma unroll
            for (int ni = 0; ni < 4; ni++) {
                acc[mi][ni] = __builtin_amdgcn_mfma_f32_16x16x32_bf16(ah[mi], bh[ni], acc[mi][ni], 0, 0, 0);
                acc[mi][ni] = __builtin_amdgcn_mfma_f32_16x16x32_bf16(ah[mi], bl[ni], acc[mi][ni], 0, 0, 0);
                acc[mi][ni] = __builtin_amdgcn_mfma_f32_16x16x32_bf16(al[mi], bh[ni], acc[mi][ni], 0, 0, 0);
            }
        __syncthreads();
    }
#pragma unroll
    for (int mi = 0; mi < 4; mi++)
#pragma unroll
        for (int ni = 0; ni < 4; ni++) {
            int col = col0 + wc * 64 + ni * 16 + l16;
#pragma unroll
            for (int r = 0; r < 4; r++) {
                int rl = blockIdx.x * 128 + wr * 64 + mi * 16 + l4 * 4 + r;
                Sc[((size_t)n * lb + rl) * SS + col] = acc[mi][ni][r];
            }
        }
}

// ---------------- row softmax: scores f32 -> P bf16 ----------------
__global__ __launch_bounds__(256) void k_softmax(const float* __restrict__ Sc,
                                                 unsigned short* __restrict__ P) {
    const size_t row = blockIdx.x;
    const float* src = Sc + row * SS;
    const int tid = threadIdx.x;
    const int lane = tid & 63, wv = tid >> 6;
    f32x4 v[2];
    float m = -3.4e38f;
#pragma unroll
    for (int i = 0; i < 2; i++) {
        v[i] = *(const f32x4*)(src + (size_t)(tid + i * 256) * 4);
#pragma unroll
        for (int j = 0; j < 4; j++) m = fmaxf(m, v[i][j]);
    }
#pragma unroll
    for (int o = 32; o > 0; o >>= 1) m = fmaxf(m, __shfl_xor(m, o, 64));
    __shared__ float redm[4];
    __shared__ float reds[4];
    if (lane == 0) redm[wv] = m;
    __syncthreads();
    m = fmaxf(fmaxf(redm[0], redm[1]), fmaxf(redm[2], redm[3]));
    float s = 0.f;
#pragma unroll
    for (int i = 0; i < 2; i++)
#pragma unroll
        for (int j = 0; j < 4; j++) {
            v[i][j] = __expf(v[i][j] - m);
            s += v[i][j];
        }
#pragma unroll
    for (int o = 32; o > 0; o >>= 1) s += __shfl_xor(s, o, 64);
    if (lane == 0) reds[wv] = s;
    __syncthreads();
    s = reds[0] + reds[1] + reds[2] + reds[3];
    float inv = 1.0f / s;
#pragma unroll
    for (int i = 0; i < 2; i++) {
        u16x4 h;
#pragma unroll
        for (int j = 0; j < 4; j++) h[j] = f2bf(v[i][j] * inv);
        *(u16x4*)(P + row * SS + (size_t)(tid + i * 256) * 4) = h;
    }
}

// ---------------- PV GEMM: out[n, lb, 1024] = P x Vt^T (bf16) ----------------
__global__ __launch_bounds__(256, 2) void k_pv(const unsigned short* __restrict__ P,
                                               const unsigned short* __restrict__ Vt,
                                               float* __restrict__ Out,
                                               int band0, int lb) {
    __shared__ __align__(16) unsigned short Ab[128 * 32], Bb[128 * 32];
    const int tid = threadIdx.x;
    const int lane = tid & 63, wv = tid >> 6;
    const int wr = wv >> 1, wc = wv & 1;
    const int l16 = lane & 15, l4 = lane >> 4;
    const int n = blockIdx.z;
    const size_t arow0 = (size_t)n * lb + blockIdx.x * 128;  // P rows (band local)
    const size_t brow0 = (size_t)n * DD + blockIdx.y * 128;  // Vt rows
    const int col0 = blockIdx.y * 128;

    f32x4 acc[4][4];
#pragma unroll
    for (int mi = 0; mi < 4; mi++)
#pragma unroll
        for (int ni = 0; ni < 4; ni++) acc[mi][ni] = (f32x4){0.f, 0.f, 0.f, 0.f};

    for (int kt = 0; kt < SS / 32; ++kt) {
        int k0 = kt * 32;
        stage_16b(Ab, P + arow0 * SS + k0, SS, tid);
        stage_16b(Bb, Vt + brow0 * SS + k0, SS, tid);
        __syncthreads();
        bf16x8 a[4], b[4];
#pragma unroll
        for (int mi = 0; mi < 4; mi++) a[mi] = ldfrag(Ab, wr * 64 + mi * 16 + l16, l4);
#pragma unroll
        for (int ni = 0; ni < 4; ni++) b[ni] = ldfrag(Bb, wc * 64 + ni * 16 + l16, l4);
#pragma unroll
        for (int mi = 0; mi < 4; mi++)
#pragma unroll
            for (int ni = 0; ni < 4; ni++)
                acc[mi][ni] = __builtin_amdgcn_mfma_f32_16x16x32_bf16(a[mi], b[ni], acc[mi][ni], 0, 0, 0);
        __syncthreads();
    }
#pragma unroll
    for (int mi = 0; mi < 4; mi++)
#pragma unroll
        for (int ni = 0; ni < 4; ni++) {
            int col = col0 + wc * 64 + ni * 16 + l16;
#pragma unroll
            for (int r = 0; r < 4; r++) {
                size_t row = (size_t)n * LL + band0 + blockIdx.x * 128 + wr * 64 + mi * 16 + l4 * 4 + r;
                Out[row * DD + col] = acc[mi][ni][r];
            }
        }
}

extern "C" void kernel_launch(void* const* d_in, const int* in_sizes, int n_in,
                              void* d_out, int out_size, void* d_ws, size_t ws_size,
                              hipStream_t stream) {
    const float* key   = (const float*)d_in[0];
    const float* query = (const float*)d_in[1];
    const float* value = (const float*)d_in[2];
    const float* W     = (const float*)d_in[3];
    const float* bias  = (const float*)d_in[4];
    float* out = (float*)d_out;
    char* ws = (char*)d_ws;

    const size_t szW  = (size_t)DD * DD * 2;        // 2 MiB
    const size_t szQP = (size_t)NB * LL * DD * 2;   // 32 MiB
    const size_t szK  = (size_t)NB * SS * DD * 2;   // 32 MiB
    const size_t szVt = (size_t)NB * DD * SS * 2;   // 32 MiB
    size_t off = 0;
    unsigned short* Wf   = (unsigned short*)(ws + off); off += szW;
    unsigned short* QPhi = (unsigned short*)(ws + off); off += szQP;
    unsigned short* QPlo = (unsigned short*)(ws + off); off += szQP;
    unsigned short* Vt   = (unsigned short*)(ws + off); off += szVt;

    // optional pre-split Key buffers
    const size_t bandBytes128 = (size_t)NB * 128 * SS * 6;
    bool presplit = (off + 2 * szK + bandBytes128) <= ws_size;
    unsigned short* Khi = nullptr; unsigned short* Klo = nullptr;
    if (presplit) {
        Khi = (unsigned short*)(ws + off); off += szK;
        Klo = (unsigned short*)(ws + off); off += szK;
    }
    int lb = 512;
    while (lb > 128 && off + (size_t)NB * lb * SS * 6 > ws_size) lb >>= 1;
    float* Sc = (float*)(ws + off); off += (size_t)NB * lb * SS * 4;
    unsigned short* P = (unsigned short*)(ws + off);

    k_wf16<<<dim3((DD * DD) / (4 * 256)), 256, 0, stream>>>(W, Wf);
    k_transv<<<dim3(SS / 64, DD / 64, NB), 256, 0, stream>>>(value, Vt);
    if (presplit)
        k_splitk<<<dim3((NB * SS * DD) / (4 * 256)), 256, 0, stream>>>(key, Khi, Klo);
    k_qproj<<<dim3((NB * LL) / 128, DD / 128), 256, 0, stream>>>(query, Wf, bias, QPhi, QPlo);

    const int nbands = LL / lb;
    for (int b = 0; b < nbands; b++) {
        int band0 = b * lb;
        if (presplit)
            k_score<true><<<dim3(lb / 128, SS / 128, NB), 256, 0, stream>>>(QPhi, QPlo, Khi, Klo, key, Sc, band0, lb);
        else
            k_score<false><<<dim3(lb / 128, SS / 128, NB), 256, 0, stream>>>(QPhi, QPlo, Khi, Klo, key, Sc, band0, lb);
        k_softmax<<<dim3(NB * lb), 256, 0, stream>>>(Sc, P);
        k_pv<<<dim3(lb / 128, DD / 128, NB), 256, 0, stream>>>(P, Vt, out, band0, lb);
    }
    (void)in_sizes; (void)n_in; (void)out_size; (void)ws_size;
}

// Round 3
// 552.243 us; speedup vs baseline: 1.1585x; 1.0099x over previous
//
#include <hip/hip_runtime.h>
#include <stdint.h>

#define NB 8
#define LL 2048
#define SS 2048
#define DD 1024

typedef __attribute__((ext_vector_type(4))) float f32x4;
typedef __attribute__((ext_vector_type(8))) short bf16x8;
typedef __attribute__((ext_vector_type(8))) _Float16 f16x8;
typedef __attribute__((ext_vector_type(4))) unsigned short u16x4;
typedef __attribute__((ext_vector_type(8))) unsigned short u16x8;

__device__ __forceinline__ unsigned short f2bf(float x) {
    unsigned int u = __builtin_bit_cast(unsigned int, x);
    u += 0x7FFFu + ((u >> 16) & 1u);   // round-to-nearest-even
    return (unsigned short)(u >> 16);
}
__device__ __forceinline__ float bf2f(unsigned short h) {
    unsigned int u = ((unsigned int)h) << 16;
    return __builtin_bit_cast(float, u);
}
__device__ __forceinline__ unsigned short f2h(float x) {
    return __builtin_bit_cast(unsigned short, (_Float16)x);
}

__device__ __forceinline__ void gload16(const void* g, void* l) {
    __builtin_amdgcn_global_load_lds(
        (const __attribute__((address_space(1))) unsigned int*)g,
        (__attribute__((address_space(3))) unsigned int*)l, 16, 0, 0);
}

// ---- swizzled [128][32]-u16 tile staging (64B rows, 4x16B chunks) ----
// physical chunk = logical chunk ^ ((row>>1)&3)  -> 8 distinct banks over 16
// rows -> 2-way (free) on ds_read_b128. Source is pre-swizzled (rule #21).
__device__ __forceinline__ void stage_16b_swz(unsigned short* lds, const unsigned short* g,
                                              int ldk, int tid) {
#pragma unroll
    for (int i = 0; i < 2; i++) {
        int seg = i * 256 + tid;
        int r = seg >> 2, pc = seg & 3;
        int c = pc ^ ((r >> 1) & 3);
        gload16(g + (size_t)r * ldk + c * 8, lds + seg * 8);
    }
}
__device__ __forceinline__ bf16x8 ldfrag_swz(const unsigned short* lds, int row, int l4) {
    int pc = l4 ^ ((row >> 1) & 3);
    return *(const bf16x8*)&lds[row * 32 + pc * 8];
}
__device__ __forceinline__ f16x8 ldfrag16_swz(const unsigned short* lds, int row, int l4) {
    int pc = l4 ^ ((row >> 1) & 3);
    return *(const f16x8*)&lds[row * 32 + pc * 8];
}

// ---- swizzled [128][32]-f32 tile staging (128B rows, 8x16B chunks) ----
// physical chunk = logical chunk ^ (row&7) -> full-bank spread, 2-way.
__device__ __forceinline__ void stage_f32_swz(float* lds, const float* g,
                                              int ldk, int tid) {
#pragma unroll
    for (int i = 0; i < 4; i++) {
        int seg = i * 256 + tid;
        int r = seg >> 3, pc = seg & 7;
        int c = pc ^ (r & 7);
        gload16(g + (size_t)r * ldk + c * 4, lds + seg * 4);
    }
}
__device__ __forceinline__ f16x8 ldfragA_f16(const float* lds, int row, int l4) {
    int p0 = (2 * l4) ^ (row & 7);
    int p1 = (2 * l4 + 1) ^ (row & 7);
    f32x4 x0 = *(const f32x4*)&lds[row * 32 + p0 * 4];
    f32x4 x1 = *(const f32x4*)&lds[row * 32 + p1 * 4];
    f16x8 r;
    r[0] = (_Float16)x0[0]; r[1] = (_Float16)x0[1];
    r[2] = (_Float16)x0[2]; r[3] = (_Float16)x0[3];
    r[4] = (_Float16)x1[0]; r[5] = (_Float16)x1[1];
    r[6] = (_Float16)x1[2]; r[7] = (_Float16)x1[3];
    return r;
}

// Fallback: stage fp32 source -> split hi/lo bf16 via registers, swizzled layout.
__device__ __forceinline__ void stage_cvt_swz(unsigned short* ldsH, unsigned short* ldsL,
                                              const float* g, int ldk, int tid) {
#pragma unroll
    for (int i = 0; i < 4; i++) {
        int seg = i * 256 + tid;
        int r = seg >> 3, sc = seg & 7;        // 8-byte subchunk 0..7
        int chunk = sc >> 1, sub = sc & 1;
        int pchunk = chunk ^ ((r >> 1) & 3);
        int dst = r * 32 + pchunk * 8 + sub * 4;
        f32x4 x = *(const f32x4*)(g + (size_t)r * ldk + sc * 4);
        u16x4 hv, lv;
#pragma unroll
        for (int j = 0; j < 4; j++) {
            unsigned short h = f2bf(x[j]);
            hv[j] = h;
            lv[j] = f2bf(x[j] - bf2f(h));
        }
        *(u16x4*)&ldsH[dst] = hv;
        *(u16x4*)&ldsL[dst] = lv;
    }
}

// ---------------- W -> fp16 ----------------
__global__ __launch_bounds__(256) void k_wf16(const float* __restrict__ W,
                                              unsigned short* __restrict__ Wf) {
    int idx = blockIdx.x * 256 + threadIdx.x;
    f32x4 x = *(const f32x4*)(W + (size_t)idx * 4);
    u16x4 h;
#pragma unroll
    for (int j = 0; j < 4; j++) h[j] = f2h(x[j]);
    *(u16x4*)(Wf + (size_t)idx * 4) = h;
}

// ---------------- Key -> hi/lo bf16 split ----------------
__global__ __launch_bounds__(256) void k_splitk(const float* __restrict__ K,
                                                unsigned short* __restrict__ Khi,
                                                unsigned short* __restrict__ Klo) {
    size_t idx = (size_t)blockIdx.x * 256 + threadIdx.x;
    f32x4 x = *(const f32x4*)(K + idx * 4);
    u16x4 h, l;
#pragma unroll
    for (int j = 0; j < 4; j++) {
        unsigned short hh = f2bf(x[j]);
        h[j] = hh;
        l[j] = f2bf(x[j] - bf2f(hh));
    }
    *(u16x4*)(Khi + idx * 4) = h;
    *(u16x4*)(Klo + idx * 4) = l;
}

// ---------------- V transpose: [n,s,d] f32 -> [n,d,s] bf16 ----------------
__global__ __launch_bounds__(256) void k_transv(const float* __restrict__ V,
                                                unsigned short* __restrict__ Vt) {
    __shared__ float t[64][65];
    const int n = blockIdx.z;
    const int s0 = blockIdx.x * 64, d0 = blockIdx.y * 64;
    const int tid = threadIdx.x;
    const float* src = V + ((size_t)n * SS + s0) * DD + d0;
#pragma unroll
    for (int i = 0; i < 4; i++) {
        int seg = i * 256 + tid;
        int r = seg >> 4, c4 = (seg & 15) * 4;
        f32x4 x = *(const f32x4*)(src + (size_t)r * DD + c4);
        t[r][c4 + 0] = x[0]; t[r][c4 + 1] = x[1];
        t[r][c4 + 2] = x[2]; t[r][c4 + 3] = x[3];
    }
    __syncthreads();
    const int dl = tid >> 2, sc = (tid & 3) * 16;
    u16x8 o0, o1;
#pragma unroll
    for (int j = 0; j < 8; j++) o0[j] = f2bf(t[sc + j][dl]);
#pragma unroll
    for (int j = 0; j < 8; j++) o1[j] = f2bf(t[sc + 8 + j][dl]);
    unsigned short* dst = Vt + ((size_t)n * DD + d0 + dl) * SS + s0 + sc;
    *(u16x8*)dst = o0;
    *(u16x8*)(dst + 8) = o1;
}

// ---------------- q_proj GEMM: f32-staged A (in-reg cvt), fp16 MFMA ----------------
__global__ __launch_bounds__(256, 2) void k_qproj(const float* __restrict__ Q,
                                                  const unsigned short* __restrict__ Wf,
                                                  const float* __restrict__ bias,
                                                  unsigned short* __restrict__ QPhi,
                                                  unsigned short* __restrict__ QPlo) {
    __shared__ __align__(16) float Af[128 * 32];
    __shared__ __align__(16) unsigned short Bw[128 * 32];
    const int tid = threadIdx.x;
    const int lane = tid & 63, wv = tid >> 6;
    const int wr = wv >> 1, wc = wv & 1;
    const int l16 = lane & 15, l4 = lane >> 4;
    const size_t row0 = (size_t)blockIdx.x * 128;
    const int col0 = blockIdx.y * 128;

    f32x4 acc[4][4];
#pragma unroll
    for (int mi = 0; mi < 4; mi++)
#pragma unroll
        for (int ni = 0; ni < 4; ni++) acc[mi][ni] = (f32x4){0.f, 0.f, 0.f, 0.f};

    for (int kt = 0; kt < DD / 32; ++kt) {
        int k0 = kt * 32;
        stage_f32_swz(Af, Q + row0 * DD + k0, DD, tid);
        stage_16b_swz(Bw, Wf + (size_t)col0 * DD + k0, DD, tid);
        __syncthreads();
        f16x8 a[4], b[4];
#pragma unroll
        for (int mi = 0; mi < 4; mi++) a[mi] = ldfragA_f16(Af, wr * 64 + mi * 16 + l16, l4);
#pragma unroll
        for (int ni = 0; ni < 4; ni++) b[ni] = ldfrag16_swz(Bw, wc * 64 + ni * 16 + l16, l4);
#pragma unroll
        for (int mi = 0; mi < 4; mi++)
#pragma unroll
            for (int ni = 0; ni < 4; ni++)
                acc[mi][ni] = __builtin_amdgcn_mfma_f32_16x16x32_f16(a[mi], b[ni], acc[mi][ni], 0, 0, 0);
        __syncthreads();
    }
#pragma unroll
    for (int mi = 0; mi < 4; mi++)
#pragma unroll
        for (int ni = 0; ni < 4; ni++) {
            int col = col0 + wc * 64 + ni * 16 + l16;
            float bv = bias[col];
#pragma unroll
            for (int r = 0; r < 4; r++) {
                size_t row = row0 + wr * 64 + mi * 16 + l4 * 4 + r;
                float v = acc[mi][ni][r] + bv;
                unsigned short h = f2bf(v);
                QPhi[row * DD + col] = h;
                QPlo[row * DD + col] = f2bf(v - bf2f(h));
            }
        }
}

// ---------------- score GEMM: scores = qp x key^T (3-pass split bf16) ----------------
template <bool PRESPLIT>
__global__ __launch_bounds__(256, 2) void k_score(const unsigned short* __restrict__ QPhi,
                                                  const unsigned short* __restrict__ QPlo,
                                                  const unsigned short* __restrict__ Khi,
                                                  const unsigned short* __restrict__ Klo,
                                                  const float* __restrict__ Key,
                                                  float* __restrict__ Sc,
                                                  int band0, int lb) {
    __shared__ __align__(16) unsigned short Ah[128 * 32], Al[128 * 32];
    __shared__ __align__(16) unsigned short Bh[128 * 32], Bl[128 * 32];
    const int tid = threadIdx.x;
    const int lane = tid & 63, wv = tid >> 6;
    const int wr = wv >> 1, wc = wv & 1;
    const int l16 = lane & 15, l4 = lane >> 4;
    const int n = blockIdx.z;
    const size_t arow0 = (size_t)n * LL + band0 + blockIdx.x * 128;
    const size_t krow0 = (size_t)n * SS + blockIdx.y * 128;
    const int col0 = blockIdx.y * 128;

    f32x4 acc[4][4];
#pragma unroll
    for (int mi = 0; mi < 4; mi++)
#pragma unroll
        for (int ni = 0; ni < 4; ni++) acc[mi][ni] = (f32x4){0.f, 0.f, 0.f, 0.f};

    for (int kt = 0; kt < DD / 32; ++kt) {
        int k0 = kt * 32;
        stage_16b_swz(Ah, QPhi + arow0 * DD + k0, DD, tid);
        stage_16b_swz(Al, QPlo + arow0 * DD + k0, DD, tid);
        if constexpr (PRESPLIT) {
            stage_16b_swz(Bh, Khi + krow0 * DD + k0, DD, tid);
            stage_16b_swz(Bl, Klo + krow0 * DD + k0, DD, tid);
        } else {
            stage_cvt_swz(Bh, Bl, Key + krow0 * DD + k0, DD, tid);
        }
        __syncthreads();
        bf16x8 ah[4], al[4], bh[4], bl[4];
#pragma unroll
        for (int mi = 0; mi < 4; mi++) {
            int r = wr * 64 + mi * 16 + l16;
            ah[mi] = ldfrag_swz(Ah, r, l4);
            al[mi] = ldfrag_swz(Al, r, l4);
        }
#pragma unroll
        for (int ni = 0; ni < 4; ni++) {
            int r = wc * 64 + ni * 16 + l16;
            bh[ni] = ldfrag_swz(Bh, r, l4);
            bl[ni] = ldfrag_swz(Bl, r, l4);
        }
#pragma unroll
        for (int mi = 0; mi < 4; mi++)
#pragma unroll
            for (int ni = 0; ni < 4; ni++) {
                acc[mi][ni] = __builtin_amdgcn_mfma_f32_16x16x32_bf16(ah[mi], bh[ni], acc[mi][ni], 0, 0, 0);
                acc[mi][ni] = __builtin_amdgcn_mfma_f32_16x16x32_bf16(ah[mi], bl[ni], acc[mi][ni], 0, 0, 0);
                acc[mi][ni] = __builtin_amdgcn_mfma_f32_16x16x32_bf16(al[mi], bh[ni], acc[mi][ni], 0, 0, 0);
            }
        __syncthreads();
    }
#pragma unroll
    for (int mi = 0; mi < 4; mi++)
#pragma unroll
        for (int ni = 0; ni < 4; ni++) {
            int col = col0 + wc * 64 + ni * 16 + l16;
#pragma unroll
            for (int r = 0; r < 4; r++) {
                int rl = blockIdx.x * 128 + wr * 64 + mi * 16 + l4 * 4 + r;
                Sc[((size_t)n * lb + rl) * SS + col] = acc[mi][ni][r];
            }
        }
}

// ---------------- row softmax: scores f32 -> P bf16 ----------------
__global__ __launch_bounds__(256) void k_softmax(const float* __restrict__ Sc,
                                                 unsigned short* __restrict__ P) {
    const size_t row = blockIdx.x;
    const float* src = Sc + row * SS;
    const int tid = threadIdx.x;
    const int lane = tid & 63, wv = tid >> 6;
    f32x4 v[2];
    float m = -3.4e38f;
#pragma unroll
    for (int i = 0; i < 2; i++) {
        v[i] = *(const f32x4*)(src + (size_t)(tid + i * 256) * 4);
#pragma unroll
        for (int j = 0; j < 4; j++) m = fmaxf(m, v[i][j]);
    }
#pragma unroll
    for (int o = 32; o > 0; o >>= 1) m = fmaxf(m, __shfl_xor(m, o, 64));
    __shared__ float redm[4];
    __shared__ float reds[4];
    if (lane == 0) redm[wv] = m;
    __syncthreads();
    m = fmaxf(fmaxf(redm[0], redm[1]), fmaxf(redm[2], redm[3]));
    float s = 0.f;
#pragma unroll
    for (int i = 0; i < 2; i++)
#pragma unroll
        for (int j = 0; j < 4; j++) {
            v[i][j] = __expf(v[i][j] - m);
            s += v[i][j];
        }
#pragma unroll
    for (int o = 32; o > 0; o >>= 1) s += __shfl_xor(s, o, 64);
    if (lane == 0) reds[wv] = s;
    __syncthreads();
    s = reds[0] + reds[1] + reds[2] + reds[3];
    float inv = 1.0f / s;
#pragma unroll
    for (int i = 0; i < 2; i++) {
        u16x4 h;
#pragma unroll
        for (int j = 0; j < 4; j++) h[j] = f2bf(v[i][j] * inv);
        *(u16x4*)(P + row * SS + (size_t)(tid + i * 256) * 4) = h;
    }
}

// ---------------- PV GEMM: out = P x Vt^T (bf16) ----------------
__global__ __launch_bounds__(256, 2) void k_pv(const unsigned short* __restrict__ P,
                                               const unsigned short* __restrict__ Vt,
                                               float* __restrict__ Out,
                                               int band0, int lb) {
    __shared__ __align__(16) unsigned short Ab[128 * 32], Bb[128 * 32];
    const int tid = threadIdx.x;
    const int lane = tid & 63, wv = tid >> 6;
    const int wr = wv >> 1, wc = wv & 1;
    const int l16 = lane & 15, l4 = lane >> 4;
    const int n = blockIdx.z;
    const size_t arow0 = (size_t)n * lb + blockIdx.x * 128;
    const size_t brow0 = (size_t)n * DD + blockIdx.y * 128;
    const int col0 = blockIdx.y * 128;

    f32x4 acc[4][4];
#pragma unroll
    for (int mi = 0; mi < 4; mi++)
#pragma unroll
        for (int ni = 0; ni < 4; ni++) acc[mi][ni] = (f32x4){0.f, 0.f, 0.f, 0.f};

    for (int kt = 0; kt < SS / 32; ++kt) {
        int k0 = kt * 32;
        stage_16b_swz(Ab, P + arow0 * SS + k0, SS, tid);
        stage_16b_swz(Bb, Vt + brow0 * SS + k0, SS, tid);
        __syncthreads();
        bf16x8 a[4], b[4];
#pragma unroll
        for (int mi = 0; mi < 4; mi++) a[mi] = ldfrag_swz(Ab, wr * 64 + mi * 16 + l16, l4);
#pragma unroll
        for (int ni = 0; ni < 4; ni++) b[ni] = ldfrag_swz(Bb, wc * 64 + ni * 16 + l16, l4);
#pragma unroll
        for (int mi = 0; mi < 4; mi++)
#pragma unroll
            for (int ni = 0; ni < 4; ni++)
                acc[mi][ni] = __builtin_amdgcn_mfma_f32_16x16x32_bf16(a[mi], b[ni], acc[mi][ni], 0, 0, 0);
        __syncthreads();
    }
#pragma unroll
    for (int mi = 0; mi < 4; mi++)
#pragma unroll
        for (int ni = 0; ni < 4; ni++) {
            int col = col0 + wc * 64 + ni * 16 + l16;
#pragma unroll
            for (int r = 0; r < 4; r++) {
                size_t row = (size_t)n * LL + band0 + blockIdx.x * 128 + wr * 64 + mi * 16 + l4 * 4 + r;
                Out[row * DD + col] = acc[mi][ni][r];
            }
        }
}

extern "C" void kernel_launch(void* const* d_in, const int* in_sizes, int n_in,
                              void* d_out, int out_size, void* d_ws, size_t ws_size,
                              hipStream_t stream) {
    const float* key   = (const float*)d_in[0];
    const float* query = (const float*)d_in[1];
    const float* value = (const float*)d_in[2];
    const float* W     = (const float*)d_in[3];
    const float* bias  = (const float*)d_in[4];
    float* out = (float*)d_out;
    char* ws = (char*)d_ws;

    const size_t szW  = (size_t)DD * DD * 2;
    const size_t szQP = (size_t)NB * LL * DD * 2;
    const size_t szK  = (size_t)NB * SS * DD * 2;
    const size_t szVt = (size_t)NB * DD * SS * 2;
    size_t off = 0;
    unsigned short* Wf   = (unsigned short*)(ws + off); off += szW;
    unsigned short* QPhi = (unsigned short*)(ws + off); off += szQP;
    unsigned short* QPlo = (unsigned short*)(ws + off); off += szQP;
    unsigned short* Vt   = (unsigned short*)(ws + off); off += szVt;

    const size_t bandBytes128 = (size_t)NB * 128 * SS * 6;
    bool presplit = (off + 2 * szK + bandBytes128) <= ws_size;
    unsigned short* Khi = nullptr; unsigned short* Klo = nullptr;
    if (presplit) {
        Khi = (unsigned short*)(ws + off); off += szK;
        Klo = (unsigned short*)(ws + off); off += szK;
    }
    int lb = 512;
    while (lb > 128 && off + (size_t)NB * lb * SS * 6 > ws_size) lb >>= 1;
    float* Sc = (float*)(ws + off); off += (size_t)NB * lb * SS * 4;
    unsigned short* P = (unsigned short*)(ws + off);

    k_wf16<<<dim3((DD * DD) / (4 * 256)), 256, 0, stream>>>(W, Wf);
    k_transv<<<dim3(SS / 64, DD / 64, NB), 256, 0, stream>>>(value, Vt);
    if (presplit)
        k_splitk<<<dim3((NB * SS * DD) / (4 * 256)), 256, 0, stream>>>(key, Khi, Klo);
    k_qproj<<<dim3((NB * LL) / 128, DD / 128), 256, 0, stream>>>(query, Wf, bias, QPhi, QPlo);

    const int nbands = LL / lb;
    for (int b = 0; b < nbands; b++) {
        int band0 = b * lb;
        if (presplit)
            k_score<true><<<dim3(lb / 128, SS / 128, NB), 256, 0, stream>>>(QPhi, QPlo, Khi, Klo, key, Sc, band0, lb);
        else
            k_score<false><<<dim3(lb / 128, SS / 128, NB), 256, 0, stream>>>(QPhi, QPlo, Khi, Klo, key, Sc, band0, lb);
        k_softmax<<<dim3(NB * lb), 256, 0, stream>>>(Sc, P);
        k_pv<<<dim3(lb / 128, DD / 128, NB), 256, 0, stream>>>(P, Vt, out, band0, lb);
    }
    (void)in_sizes; (void)n_in; (void)out_size; (void)ws_size;
}

// Round 4
// 463.259 us; speedup vs baseline: 1.3810x; 1.1921x over previous
//
#include <hip/hip_runtime.h>
#include <stdint.h>

#define NB 8
#define LL 2048
#define SS 2048
#define DD 1024

typedef __attribute__((ext_vector_type(4))) float f32x4;
typedef __attribute__((ext_vector_type(8))) _Float16 f16x8;
typedef __attribute__((ext_vector_type(4))) unsigned short u16x4;
typedef __attribute__((ext_vector_type(8))) unsigned short u16x8;

__device__ __forceinline__ unsigned short f2h(float x) {
    return __builtin_bit_cast(unsigned short, (_Float16)x);
}

__device__ __forceinline__ void gload16(const void* g, void* l) {
    __builtin_amdgcn_global_load_lds(
        (const __attribute__((address_space(1))) unsigned int*)g,
        (__attribute__((address_space(3))) unsigned int*)l, 16, 0, 0);
}

// ---- swizzled [128][32]-u16 tile staging (64B rows, 4x16B chunks) ----
// physical chunk = logical chunk ^ ((row>>1)&3); source pre-swizzled (rule #21).
__device__ __forceinline__ void stage_u16(unsigned short* lds, const unsigned short* g,
                                          int ldk, int tid) {
#pragma unroll
    for (int i = 0; i < 2; i++) {
        int seg = i * 256 + tid;
        int r = seg >> 2, pc = seg & 3;
        int c = pc ^ ((r >> 1) & 3);
        gload16(g + (size_t)r * ldk + c * 8, lds + seg * 8);
    }
}
__device__ __forceinline__ f16x8 ldfragH(const unsigned short* lds, int row, int l4) {
    int pc = l4 ^ ((row >> 1) & 3);
    return *(const f16x8*)&lds[row * 32 + pc * 8];
}

// ---- swizzled [128][32]-f32 tile staging (128B rows, 8x16B chunks) ----
__device__ __forceinline__ void stage_f32(float* lds, const float* g,
                                          int ldk, int tid) {
#pragma unroll
    for (int i = 0; i < 4; i++) {
        int seg = i * 256 + tid;
        int r = seg >> 3, pc = seg & 7;
        int c = pc ^ (r & 7);
        gload16(g + (size_t)r * ldk + c * 4, lds + seg * 4);
    }
}
__device__ __forceinline__ f16x8 ldfragA_f16(const float* lds, int row, int l4) {
    int p0 = (2 * l4) ^ (row & 7);
    int p1 = (2 * l4 + 1) ^ (row & 7);
    f32x4 x0 = *(const f32x4*)&lds[row * 32 + p0 * 4];
    f32x4 x1 = *(const f32x4*)&lds[row * 32 + p1 * 4];
    f16x8 r;
    r[0] = (_Float16)x0[0]; r[1] = (_Float16)x0[1];
    r[2] = (_Float16)x0[2]; r[3] = (_Float16)x0[3];
    r[4] = (_Float16)x1[0]; r[5] = (_Float16)x1[1];
    r[6] = (_Float16)x1[2]; r[7] = (_Float16)x1[3];
    return r;
}

// ---------------- generic f32 -> f16 convert ----------------
__global__ __launch_bounds__(256) void k_cvt(const float* __restrict__ src,
                                             unsigned short* __restrict__ dst, int n4) {
    int idx = blockIdx.x * 256 + threadIdx.x;
    if (idx >= n4) return;
    f32x4 x = *(const f32x4*)(src + (size_t)idx * 4);
    u16x4 h;
#pragma unroll
    for (int j = 0; j < 4; j++) h[j] = f2h(x[j]);
    *(u16x4*)(dst + (size_t)idx * 4) = h;
}

// ---------------- V transpose: [n,s,d] f32 -> [n,d,s] fp16 ----------------
__global__ __launch_bounds__(256) void k_transv(const float* __restrict__ V,
                                                unsigned short* __restrict__ Vt) {
    __shared__ float t[64][65];
    const int n = blockIdx.z;
    const int s0 = blockIdx.x * 64, d0 = blockIdx.y * 64;
    const int tid = threadIdx.x;
    const float* src = V + ((size_t)n * SS + s0) * DD + d0;
#pragma unroll
    for (int i = 0; i < 4; i++) {
        int seg = i * 256 + tid;
        int r = seg >> 4, c4 = (seg & 15) * 4;
        f32x4 x = *(const f32x4*)(src + (size_t)r * DD + c4);
        t[r][c4 + 0] = x[0]; t[r][c4 + 1] = x[1];
        t[r][c4 + 2] = x[2]; t[r][c4 + 3] = x[3];
    }
    __syncthreads();
    const int dl = tid >> 2, sc = (tid & 3) * 16;
    u16x8 o0, o1;
#pragma unroll
    for (int j = 0; j < 8; j++) o0[j] = f2h(t[sc + j][dl]);
#pragma unroll
    for (int j = 0; j < 8; j++) o1[j] = f2h(t[sc + 8 + j][dl]);
    unsigned short* dst = Vt + ((size_t)n * DD + d0 + dl) * SS + s0 + sc;
    *(u16x8*)dst = o0;
    *(u16x8*)(dst + 8) = o1;
}

// ---------------- q_proj GEMM: Q(f32 staged) x Wf16 + b -> fp16 hi/lo split ----------------
__global__ __launch_bounds__(256, 3) void k_qproj(const float* __restrict__ Q,
                                                  const unsigned short* __restrict__ Wf,
                                                  const float* __restrict__ bias,
                                                  unsigned short* __restrict__ QPh,
                                                  unsigned short* __restrict__ QPl) {
    __shared__ __align__(16) float Af[2][4096];
    __shared__ __align__(16) unsigned short Bw[2][4096];
    const int tid = threadIdx.x;
    const int lane = tid & 63, wv = tid >> 6;
    const int wr = wv >> 1, wc = wv & 1;
    const int l16 = lane & 15, l4 = lane >> 4;
    const size_t row0 = (size_t)blockIdx.x * 128;
    const int col0 = blockIdx.y * 128;
    const float* gA = Q + row0 * DD;
    const unsigned short* gB = Wf + (size_t)col0 * DD;

    f32x4 acc[4][4];
#pragma unroll
    for (int mi = 0; mi < 4; mi++)
#pragma unroll
        for (int ni = 0; ni < 4; ni++) acc[mi][ni] = (f32x4){0.f, 0.f, 0.f, 0.f};

    stage_f32(Af[0], gA, DD, tid);
    stage_u16(Bw[0], gB, DD, tid);
    __syncthreads();
    int cur = 0;
    for (int kt = 0; kt < DD / 32; ++kt) {
        if (kt + 1 < DD / 32) {
            stage_f32(Af[cur ^ 1], gA + (kt + 1) * 32, DD, tid);
            stage_u16(Bw[cur ^ 1], gB + (kt + 1) * 32, DD, tid);
        }
        f16x8 a[4], b[4];
#pragma unroll
        for (int mi = 0; mi < 4; mi++) a[mi] = ldfragA_f16(Af[cur], wr * 64 + mi * 16 + l16, l4);
#pragma unroll
        for (int ni = 0; ni < 4; ni++) b[ni] = ldfragH(Bw[cur], wc * 64 + ni * 16 + l16, l4);
#pragma unroll
        for (int mi = 0; mi < 4; mi++)
#pragma unroll
            for (int ni = 0; ni < 4; ni++)
                acc[mi][ni] = __builtin_amdgcn_mfma_f32_16x16x32_f16(a[mi], b[ni], acc[mi][ni], 0, 0, 0);
        __syncthreads();
        cur ^= 1;
    }
#pragma unroll
    for (int mi = 0; mi < 4; mi++)
#pragma unroll
        for (int ni = 0; ni < 4; ni++) {
            int col = col0 + wc * 64 + ni * 16 + l16;
            float bv = bias[col];
#pragma unroll
            for (int r = 0; r < 4; r++) {
                size_t row = row0 + wr * 64 + mi * 16 + l4 * 4 + r;
                float v = acc[mi][ni][r] + bv;
                _Float16 h = (_Float16)v;
                _Float16 l = (_Float16)(v - (float)h);
                QPh[row * DD + col] = __builtin_bit_cast(unsigned short, h);
                QPl[row * DD + col] = __builtin_bit_cast(unsigned short, l);
            }
        }
}

// ---------------- score GEMM: (QPh+QPl) x Kf16^T, 2-pass fp16 ----------------
__global__ __launch_bounds__(256, 3) void k_score(const unsigned short* __restrict__ QPh,
                                                  const unsigned short* __restrict__ QPl,
                                                  const unsigned short* __restrict__ Kf,
                                                  float* __restrict__ Sc,
                                                  int band0, int lb) {
    __shared__ __align__(16) unsigned short Ah[2][4096], Al[2][4096], Bk[2][4096];
    const int tid = threadIdx.x;
    const int lane = tid & 63, wv = tid >> 6;
    const int wr = wv >> 1, wc = wv & 1;
    const int l16 = lane & 15, l4 = lane >> 4;
    const int n = blockIdx.z;
    const size_t arow0 = (size_t)n * LL + band0 + blockIdx.x * 128;
    const size_t krow0 = (size_t)n * SS + blockIdx.y * 128;
    const int col0 = blockIdx.y * 128;
    const unsigned short* gAh = QPh + arow0 * DD;
    const unsigned short* gAl = QPl + arow0 * DD;
    const unsigned short* gB  = Kf + krow0 * DD;

    f32x4 acc[4][4];
#pragma unroll
    for (int mi = 0; mi < 4; mi++)
#pragma unroll
        for (int ni = 0; ni < 4; ni++) acc[mi][ni] = (f32x4){0.f, 0.f, 0.f, 0.f};

    stage_u16(Ah[0], gAh, DD, tid);
    stage_u16(Al[0], gAl, DD, tid);
    stage_u16(Bk[0], gB, DD, tid);
    __syncthreads();
    int cur = 0;
    for (int kt = 0; kt < DD / 32; ++kt) {
        if (kt + 1 < DD / 32) {
            stage_u16(Ah[cur ^ 1], gAh + (kt + 1) * 32, DD, tid);
            stage_u16(Al[cur ^ 1], gAl + (kt + 1) * 32, DD, tid);
            stage_u16(Bk[cur ^ 1], gB + (kt + 1) * 32, DD, tid);
        }
        f16x8 ah[4], al[4], bk[4];
#pragma unroll
        for (int mi = 0; mi < 4; mi++) {
            int r = wr * 64 + mi * 16 + l16;
            ah[mi] = ldfragH(Ah[cur], r, l4);
            al[mi] = ldfragH(Al[cur], r, l4);
        }
#pragma unroll
        for (int ni = 0; ni < 4; ni++) bk[ni] = ldfragH(Bk[cur], wc * 64 + ni * 16 + l16, l4);
#pragma unroll
        for (int mi = 0; mi < 4; mi++)
#pragma unroll
            for (int ni = 0; ni < 4; ni++) {
                acc[mi][ni] = __builtin_amdgcn_mfma_f32_16x16x32_f16(ah[mi], bk[ni], acc[mi][ni], 0, 0, 0);
                acc[mi][ni] = __builtin_amdgcn_mfma_f32_16x16x32_f16(al[mi], bk[ni], acc[mi][ni], 0, 0, 0);
            }
        __syncthreads();
        cur ^= 1;
    }
#pragma unroll
    for (int mi = 0; mi < 4; mi++)
#pragma unroll
        for (int ni = 0; ni < 4; ni++) {
            int col = col0 + wc * 64 + ni * 16 + l16;
#pragma unroll
            for (int r = 0; r < 4; r++) {
                int rl = blockIdx.x * 128 + wr * 64 + mi * 16 + l4 * 4 + r;
                Sc[((size_t)n * lb + rl) * SS + col] = acc[mi][ni][r];
            }
        }
}

// ---------------- row softmax: Sc f32 -> P fp16 ----------------
__global__ __launch_bounds__(256) void k_softmax(const float* __restrict__ Sc,
                                                 unsigned short* __restrict__ P,
                                                 int lb, int PL, int band0p) {
    const int brow = blockIdx.x;             // 0 .. NB*lb-1
    const int n = brow / lb, local = brow % lb;
    const float* src = Sc + (size_t)brow * SS;
    unsigned short* dst = P + ((size_t)n * PL + band0p + local) * SS;
    const int tid = threadIdx.x;
    const int lane = tid & 63, wv = tid >> 6;
    f32x4 v[2];
    float m = -3.4e38f;
#pragma unroll
    for (int i = 0; i < 2; i++) {
        v[i] = *(const f32x4*)(src + (size_t)(tid + i * 256) * 4);
#pragma unroll
        for (int j = 0; j < 4; j++) m = fmaxf(m, v[i][j]);
    }
#pragma unroll
    for (int o = 32; o > 0; o >>= 1) m = fmaxf(m, __shfl_xor(m, o, 64));
    __shared__ float redm[4];
    __shared__ float reds[4];
    if (lane == 0) redm[wv] = m;
    __syncthreads();
    m = fmaxf(fmaxf(redm[0], redm[1]), fmaxf(redm[2], redm[3]));
    float s = 0.f;
#pragma unroll
    for (int i = 0; i < 2; i++)
#pragma unroll
        for (int j = 0; j < 4; j++) {
            v[i][j] = __expf(v[i][j] - m);
            s += v[i][j];
        }
#pragma unroll
    for (int o = 32; o > 0; o >>= 1) s += __shfl_xor(s, o, 64);
    if (lane == 0) reds[wv] = s;
    __syncthreads();
    s = reds[0] + reds[1] + reds[2] + reds[3];
    float inv = 1.0f / s;
#pragma unroll
    for (int i = 0; i < 2; i++) {
        u16x4 h;
#pragma unroll
        for (int j = 0; j < 4; j++) h[j] = f2h(v[i][j] * inv);
        *(u16x4*)(dst + (size_t)(tid + i * 256) * 4) = h;
    }
}

// ---------------- PV GEMM: P x Vt^T (fp16), f32 out ----------------
__global__ __launch_bounds__(256, 3) void k_pv(const unsigned short* __restrict__ P,
                                               const unsigned short* __restrict__ Vt,
                                               float* __restrict__ Out,
                                               int PL, int band0p, int band0o) {
    __shared__ __align__(16) unsigned short Ab[2][4096], Bb[2][4096];
    const int tid = threadIdx.x;
    const int lane = tid & 63, wv = tid >> 6;
    const int wr = wv >> 1, wc = wv & 1;
    const int l16 = lane & 15, l4 = lane >> 4;
    const int n = blockIdx.z;
    const size_t arow0 = (size_t)n * PL + band0p + blockIdx.x * 128;
    const size_t brow0 = (size_t)n * DD + blockIdx.y * 128;
    const int col0 = blockIdx.y * 128;
    const unsigned short* gA = P + arow0 * SS;
    const unsigned short* gB = Vt + brow0 * SS;

    f32x4 acc[4][4];
#pragma unroll
    for (int mi = 0; mi < 4; mi++)
#pragma unroll
        for (int ni = 0; ni < 4; ni++) acc[mi][ni] = (f32x4){0.f, 0.f, 0.f, 0.f};

    stage_u16(Ab[0], gA, SS, tid);
    stage_u16(Bb[0], gB, SS, tid);
    __syncthreads();
    int cur = 0;
    for (int kt = 0; kt < SS / 32; ++kt) {
        if (kt + 1 < SS / 32) {
            stage_u16(Ab[cur ^ 1], gA + (kt + 1) * 32, SS, tid);
            stage_u16(Bb[cur ^ 1], gB + (kt + 1) * 32, SS, tid);
        }
        f16x8 a[4], b[4];
#pragma unroll
        for (int mi = 0; mi < 4; mi++) a[mi] = ldfragH(Ab[cur], wr * 64 + mi * 16 + l16, l4);
#pragma unroll
        for (int ni = 0; ni < 4; ni++) b[ni] = ldfragH(Bb[cur], wc * 64 + ni * 16 + l16, l4);
#pragma unroll
        for (int mi = 0; mi < 4; mi++)
#pragma unroll
            for (int ni = 0; ni < 4; ni++)
                acc[mi][ni] = __builtin_amdgcn_mfma_f32_16x16x32_f16(a[mi], b[ni], acc[mi][ni], 0, 0, 0);
        __syncthreads();
        cur ^= 1;
    }
#pragma unroll
    for (int mi = 0; mi < 4; mi++)
#pragma unroll
        for (int ni = 0; ni < 4; ni++) {
            int col = col0 + wc * 64 + ni * 16 + l16;
#pragma unroll
            for (int r = 0; r < 4; r++) {
                size_t row = (size_t)n * LL + band0o + blockIdx.x * 128 + wr * 64 + mi * 16 + l4 * 4 + r;
                Out[row * DD + col] = acc[mi][ni][r];
            }
        }
}

extern "C" void kernel_launch(void* const* d_in, const int* in_sizes, int n_in,
                              void* d_out, int out_size, void* d_ws, size_t ws_size,
                              hipStream_t stream) {
    const float* key   = (const float*)d_in[0];
    const float* query = (const float*)d_in[1];
    const float* value = (const float*)d_in[2];
    const float* W     = (const float*)d_in[3];
    const float* bias  = (const float*)d_in[4];
    float* out = (float*)d_out;
    char* ws = (char*)d_ws;

    const size_t szW  = (size_t)DD * DD * 2;        // 2 MiB
    const size_t szQP = (size_t)NB * LL * DD * 2;   // 32 MiB
    const size_t szK  = (size_t)NB * SS * DD * 2;   // 32 MiB
    const size_t szVt = (size_t)NB * DD * SS * 2;   // 32 MiB
    size_t off = 0;
    unsigned short* Wf  = (unsigned short*)(ws + off); off += szW;
    unsigned short* QPh = (unsigned short*)(ws + off); off += szQP;
    unsigned short* QPl = (unsigned short*)(ws + off); off += szQP;
    unsigned short* Kf  = (unsigned short*)(ws + off); off += szK;
    unsigned short* Vt  = (unsigned short*)(ws + off); off += szVt;   // 130 MiB

    const size_t szPfull = (size_t)NB * LL * SS * 2;  // 64 MiB
    auto scBytes = [](int lb) { return (size_t)NB * lb * SS * 4; };
    auto pbBytes = [](int lb) { return (size_t)NB * lb * SS * 2; };

    bool pfull = (off + scBytes(512) + szPfull) <= ws_size;
    int lb = 512;
    float* Sc;
    unsigned short* P;
    if (pfull) {
        Sc = (float*)(ws + off); off += scBytes(512);
        P  = (unsigned short*)(ws + off);
    } else {
        while (lb > 128 && off + scBytes(lb) + pbBytes(lb) > ws_size) lb >>= 1;
        Sc = (float*)(ws + off); off += scBytes(lb);
        P  = (unsigned short*)(ws + off);
    }

    // conversions
    k_cvt<<<dim3((DD * DD / 4 + 255) / 256), 256, 0, stream>>>(W, Wf, DD * DD / 4);
    k_cvt<<<dim3(((int)((size_t)NB * SS * DD / 4) + 255) / 256), 256, 0, stream>>>(key, Kf, (int)((size_t)NB * SS * DD / 4));
    k_transv<<<dim3(SS / 64, DD / 64, NB), 256, 0, stream>>>(value, Vt);
    k_qproj<<<dim3((NB * LL) / 128, DD / 128), 256, 0, stream>>>(query, Wf, bias, QPh, QPl);

    const int nbands = LL / lb;
    for (int b = 0; b < nbands; b++) {
        int band0 = b * lb;
        k_score<<<dim3(lb / 128, SS / 128, NB), 256, 0, stream>>>(QPh, QPl, Kf, Sc, band0, lb);
        if (pfull) {
            k_softmax<<<dim3(NB * lb), 256, 0, stream>>>(Sc, P, lb, LL, band0);
        } else {
            k_softmax<<<dim3(NB * lb), 256, 0, stream>>>(Sc, P, lb, lb, 0);
            k_pv<<<dim3(lb / 128, DD / 128, NB), 256, 0, stream>>>(P, Vt, out, lb, 0, band0);
        }
    }
    if (pfull)
        k_pv<<<dim3(LL / 128, DD / 128, NB), 256, 0, stream>>>(P, Vt, out, LL, 0, 0);
    (void)in_sizes; (void)n_in; (void)out_size;
}